// Round 1
// baseline (729.486 us; speedup 1.0000x reference)
//
#include <hip/hip_runtime.h>

#define BB 4
#define VV 512
#define HH 128
#define NHH 8
#define HDD 16
#define NEG_SLOPE 0.2f

__device__ __forceinline__ float wave_reduce_sum(float v) {
    v += __shfl_xor(v, 32);
    v += __shfl_xor(v, 16);
    v += __shfl_xor(v, 8);
    v += __shfl_xor(v, 4);
    v += __shfl_xor(v, 2);
    v += __shfl_xor(v, 1);
    return v;
}

__device__ __forceinline__ float wave_reduce_max(float v) {
    v = fmaxf(v, __shfl_xor(v, 32));
    v = fmaxf(v, __shfl_xor(v, 16));
    v = fmaxf(v, __shfl_xor(v, 8));
    v = fmaxf(v, __shfl_xor(v, 4));
    v = fmaxf(v, __shfl_xor(v, 2));
    v = fmaxf(v, __shfl_xor(v, 1));
    return v;
}

// Kernel 1: h = x @ W_w^T + W_b ; s_i = <h_row, a_i_flat> ; s_j = <h_row, a_j_flat>
// One block per (b,v) row, 128 threads (thread o computes h[row, o]).
__global__ __launch_bounds__(128) void k_h_scores(
    const float* __restrict__ x, const float* __restrict__ W_w,
    const float* __restrict__ W_b, const float* __restrict__ a,
    float* __restrict__ h_ws, float* __restrict__ si_ws, float* __restrict__ sj_ws) {
    const int row = blockIdx.x;      // b*V + v
    const int tid = threadIdx.x;     // 0..127
    __shared__ float xs[HH];
    __shared__ float red[4];

    xs[tid] = x[row * HH + tid];
    __syncthreads();

    float acc = W_b[tid];
    const float4* wrow = (const float4*)(W_w + (size_t)tid * HH);
    const float4* xv = (const float4*)xs;
#pragma unroll
    for (int k = 0; k < HH / 4; ++k) {
        float4 w = wrow[k];
        float4 xx = xv[k];
        acc = fmaf(w.x, xx.x, acc);
        acc = fmaf(w.y, xx.y, acc);
        acc = fmaf(w.z, xx.z, acc);
        acc = fmaf(w.w, xx.w, acc);
    }
    h_ws[(size_t)row * HH + tid] = acc;

    // a layout: (1, NH, 2*HD). a_i[n,k] = a[n*32 + k], a_j[n,k] = a[n*32 + 16 + k].
    // h position p = n*HD + k  ->  n = p>>4, k = p&15
    const int n = tid >> 4, k = tid & 15;
    const float ai = a[n * 2 * HDD + k];
    const float aj = a[n * 2 * HDD + HDD + k];
    float pi = acc * ai;
    float pj = acc * aj;
    pi = wave_reduce_sum(pi);
    pj = wave_reduce_sum(pj);
    const int lane = tid & 63, wid = tid >> 6;
    if (lane == 0) { red[wid] = pi; red[2 + wid] = pj; }
    __syncthreads();
    if (tid == 0) si_ws[row] = red[0] + red[1];
    if (tid == 1) sj_ws[row] = red[2] + red[3];
}

// Kernel 2: per (b,i) row: edge-gate mean, leaky-relu score, softmax over j,
// attended = sum_j w_j * h[b,j,:], out = attended @ Wo_w^T + Wo_b.
// One block per (b,i), 256 threads.
__global__ __launch_bounds__(256) void k_attn(
    const float* __restrict__ edge_gate,
    const float* __restrict__ h_ws,
    const float* __restrict__ si_ws, const float* __restrict__ sj_ws,
    const float* __restrict__ Wo_w, const float* __restrict__ Wo_b,
    float* __restrict__ out) {
    const int bi = blockIdx.x;     // b*V + i
    const int b = bi >> 9;         // V = 512
    const int tid = threadIdx.x;   // 0..255

    __shared__ float sm[VV];       // scores -> exp weights
    __shared__ float sjs[VV];      // s_j for this b
    __shared__ float att[256];     // attended partials -> attended
    __shared__ float red[4];

    sjs[tid] = sj_ws[b * VV + tid];
    sjs[tid + 256] = sj_ws[b * VV + tid + 256];
    const float si = si_ws[bi];
    __syncthreads();

    // ---- Phase A: stream edge_gate[b,i,:,:] (512 KB... 512*128*4B = 256 KB contiguous)
    // 32 lanes per j, each lane one float4 (32*4 = 128 elems = full mean reduction).
    const float4* eg = (const float4*)(edge_gate + (size_t)bi * (VV * HH));
    const int grp = tid >> 5;   // 0..7  -> 8 j's per loop iteration
    const int lg = tid & 31;
    for (int t = 0; t < VV / 8; ++t) {
        const int j = t * 8 + grp;
        float4 v = eg[j * (HH / 4) + lg];
        float p = v.x + v.y + v.z + v.w;
        p += __shfl_xor(p, 16);
        p += __shfl_xor(p, 8);
        p += __shfl_xor(p, 4);
        p += __shfl_xor(p, 2);
        p += __shfl_xor(p, 1);
        if (lg == 0) {
            float z = si + sjs[j];
            z = z > 0.f ? z : NEG_SLOPE * z;
            sm[j] = z * (p * (1.0f / HH));   // leaky_relu(s) * mean(edge_gate)
        }
    }
    __syncthreads();

    // ---- Phase B: softmax over j (512 entries), 2 per thread
    const int lane = tid & 63, wid = tid >> 6;
    float m = fmaxf(sm[tid], sm[tid + 256]);
    m = wave_reduce_max(m);
    if (lane == 0) red[wid] = m;
    __syncthreads();
    m = fmaxf(fmaxf(red[0], red[1]), fmaxf(red[2], red[3]));

    float e0 = __expf(sm[tid] - m);
    float e1 = __expf(sm[tid + 256] - m);
    sm[tid] = e0;
    sm[tid + 256] = e1;
    float se = e0 + e1;
    se = wave_reduce_sum(se);
    __syncthreads();                 // red max-partials consumed; sm e-values written
    if (lane == 0) red[wid] = se;
    __syncthreads();
    const float inv = 1.0f / (red[0] + red[1] + red[2] + red[3]);

    // ---- Phase C: attended[d] = inv * sum_j e_j * h[b,j,d]
    const int d = tid & 127, half = tid >> 7;
    const float* hb = h_ws + (size_t)b * VV * HH;
    float acc = 0.f;
#pragma unroll 4
    for (int j = half; j < VV; j += 2)
        acc = fmaf(sm[j], hb[j * HH + d], acc);
    att[tid] = acc;
    __syncthreads();
    if (tid < HH) att[tid] = (att[tid] + att[tid + 128]) * inv;
    __syncthreads();

    // ---- Phase D: out[bi,o] = attended @ Wo_w[o,:] + Wo_b[o]
    if (tid < HH) {
        const float4* wrow = (const float4*)(Wo_w + (size_t)tid * HH);
        const float4* av = (const float4*)att;
        float acc2 = Wo_b[tid];
#pragma unroll
        for (int k = 0; k < HH / 4; ++k) {
            float4 w = wrow[k];
            float4 aa = av[k];
            acc2 = fmaf(w.x, aa.x, acc2);
            acc2 = fmaf(w.y, aa.y, acc2);
            acc2 = fmaf(w.z, aa.z, acc2);
            acc2 = fmaf(w.w, aa.w, acc2);
        }
        out[(size_t)bi * HH + tid] = acc2;
    }
}

extern "C" void kernel_launch(void* const* d_in, const int* in_sizes, int n_in,
                              void* d_out, int out_size, void* d_ws, size_t ws_size,
                              hipStream_t stream) {
    const float* x         = (const float*)d_in[0];
    const float* edge_gate = (const float*)d_in[1];
    const float* W_w       = (const float*)d_in[2];
    const float* W_b       = (const float*)d_in[3];
    const float* a         = (const float*)d_in[4];
    const float* Wo_w      = (const float*)d_in[5];
    const float* Wo_b      = (const float*)d_in[6];
    float* out = (float*)d_out;

    float* h_ws  = (float*)d_ws;              // B*V*H floats = 1 MiB
    float* si_ws = h_ws + (size_t)BB * VV * HH;
    float* sj_ws = si_ws + (size_t)BB * VV;

    k_h_scores<<<BB * VV, 128, 0, stream>>>(x, W_w, W_b, a, h_ws, si_ws, sj_ws);
    k_attn<<<BB * VV, 256, 0, stream>>>(edge_gate, h_ws, si_ws, sj_ws, Wo_w, Wo_b, out);
}

// Round 2
// 718.955 us; speedup vs baseline: 1.0146x; 1.0146x over previous
//
#include <hip/hip_runtime.h>

#define BB 4
#define VV 512
#define HH 128
#define NHH 8
#define HDD 16
#define NEG_SLOPE 0.2f

__device__ __forceinline__ float wave_reduce_sum(float v) {
    v += __shfl_xor(v, 32);
    v += __shfl_xor(v, 16);
    v += __shfl_xor(v, 8);
    v += __shfl_xor(v, 4);
    v += __shfl_xor(v, 2);
    v += __shfl_xor(v, 1);
    return v;
}

__device__ __forceinline__ float wave_reduce_max(float v) {
    v = fmaxf(v, __shfl_xor(v, 32));
    v = fmaxf(v, __shfl_xor(v, 16));
    v = fmaxf(v, __shfl_xor(v, 8));
    v = fmaxf(v, __shfl_xor(v, 4));
    v = fmaxf(v, __shfl_xor(v, 2));
    v = fmaxf(v, __shfl_xor(v, 1));
    return v;
}

// Kernel 1: h = x @ W_w^T + W_b ; s_i = <h_row, a_i_flat> ; s_j = <h_row, a_j_flat>
// One block per (b,v) row, 128 threads (thread o computes h[row, o]).
__global__ __launch_bounds__(128) void k_h_scores(
    const float* __restrict__ x, const float* __restrict__ W_w,
    const float* __restrict__ W_b, const float* __restrict__ a,
    float* __restrict__ h_ws, float* __restrict__ si_ws, float* __restrict__ sj_ws) {
    const int row = blockIdx.x;      // b*V + v
    const int tid = threadIdx.x;     // 0..127
    __shared__ float xs[HH];
    __shared__ float red[4];

    xs[tid] = x[row * HH + tid];
    __syncthreads();

    float acc = W_b[tid];
    const float4* wrow = (const float4*)(W_w + (size_t)tid * HH);
    const float4* xv = (const float4*)xs;
#pragma unroll
    for (int k = 0; k < HH / 4; ++k) {
        float4 w = wrow[k];
        float4 xx = xv[k];
        acc = fmaf(w.x, xx.x, acc);
        acc = fmaf(w.y, xx.y, acc);
        acc = fmaf(w.z, xx.z, acc);
        acc = fmaf(w.w, xx.w, acc);
    }
    h_ws[(size_t)row * HH + tid] = acc;

    // a layout: (1, NH, 2*HD). a_i[n,k] = a[n*32+k], a_j[n,k] = a[n*32+16+k].
    const int n = tid >> 4, k = tid & 15;
    const float ai = a[n * 2 * HDD + k];
    const float aj = a[n * 2 * HDD + HDD + k];
    float pi = wave_reduce_sum(acc * ai);
    float pj = wave_reduce_sum(acc * aj);
    const int lane = tid & 63, wid = tid >> 6;
    if (lane == 0) { red[wid] = pi; red[2 + wid] = pj; }
    __syncthreads();
    if (tid == 0) si_ws[row] = red[0] + red[1];
    if (tid == 1) sj_ws[row] = red[2] + red[3];
}

// Kernel 2: per (b,i): edge-gate mean, leaky-relu score, softmax over j,
// attended = sum_j w_j * h[b,j,:], out = attended @ Wo_w^T + Wo_b.
// One block per (b,i), 256 threads.
__global__ __launch_bounds__(256) void k_attn(
    const float* __restrict__ edge_gate,
    const float* __restrict__ h_ws,
    const float* __restrict__ si_ws, const float* __restrict__ sj_ws,
    const float* __restrict__ Wo_w, const float* __restrict__ Wo_b,
    float* __restrict__ out) {
    const int bi = blockIdx.x;     // b*V + i
    const int b = bi >> 9;         // V = 512
    const int tid = threadIdx.x;   // 0..255

    __shared__ float sm[VV];         // scores -> exp weights (2 KB)
    __shared__ float sjs[VV];        // s_j for this b        (2 KB)
    __shared__ float attp[8][HH];    // attended partials     (4 KB)
    __shared__ float att[HH];        // attended              (512 B)
    __shared__ float red[4];

    sjs[tid] = sj_ws[b * VV + tid];
    sjs[tid + 256] = sj_ws[b * VV + tid + 256];
    const float si = si_ws[bi];
    __syncthreads();

    // ---- Phase A: mean over H of edge_gate[b,i,j,:] fused with leaky-relu score.
    // 4 lanes per j (quad): each lane sums 8 independent float4 chunks
    // (quad covers the full 512-B row), then 2 quad-local shuffles.
    // Per thread: 8 outer iters x 8 independent loads -> deep vmem pipeline.
    {
        const int grp = tid >> 5;        // 0..7 (32-lane group)
        const int lg  = tid & 31;
        const int q   = lg >> 2;         // quad within group: 0..7
        const int ql  = lg & 3;          // lane within quad
        const float4* eg = (const float4*)(edge_gate + (size_t)bi * (VV * HH));
#pragma unroll
        for (int t = 0; t < VV / 64; ++t) {          // 8 iterations
            const int j = t * 64 + grp * 8 + q;
            const float4* row = eg + (size_t)j * (HH / 4);
            float s = 0.f;
#pragma unroll
            for (int u = 0; u < 8; ++u) {            // 8 independent 16-B loads
                float4 v = row[(u << 2) + ql];
                s += (v.x + v.y) + (v.z + v.w);
            }
            s += __shfl_xor(s, 1);
            s += __shfl_xor(s, 2);
            if (ql == 0) {
                float z = si + sjs[j];
                z = z > 0.f ? z : NEG_SLOPE * z;
                sm[j] = z * (s * (1.0f / HH));
            }
        }
    }
    __syncthreads();

    // ---- Phase B: softmax over j (512 entries), 2 per thread
    const int lane = tid & 63, wid = tid >> 6;
    float m = fmaxf(sm[tid], sm[tid + 256]);
    m = wave_reduce_max(m);
    if (lane == 0) red[wid] = m;
    __syncthreads();
    m = fmaxf(fmaxf(red[0], red[1]), fmaxf(red[2], red[3]));

    float e0 = __expf(sm[tid] - m);
    float e1 = __expf(sm[tid + 256] - m);
    sm[tid] = e0;
    sm[tid + 256] = e1;
    float se = wave_reduce_sum(e0 + e1);
    __syncthreads();
    if (lane == 0) red[wid] = se;
    __syncthreads();
    const float inv = 1.0f / (red[0] + red[1] + red[2] + red[3]);

    // ---- Phase C: attended[d] = inv * sum_j e_j * h[b,j,d], float4 over d
    {
        const int part = tid >> 5;      // 0..7: j-slice
        const int dq   = tid & 31;      // float4 column
        const float4* hb4 = (const float4*)(h_ws + (size_t)b * VV * HH);
        float4 acc = {0.f, 0.f, 0.f, 0.f};
#pragma unroll 8
        for (int j = part; j < VV; j += 8) {
            const float w = sm[j];      // LDS broadcast within group
            float4 hv = hb4[(size_t)j * (HH / 4) + dq];
            acc.x = fmaf(w, hv.x, acc.x);
            acc.y = fmaf(w, hv.y, acc.y);
            acc.z = fmaf(w, hv.z, acc.z);
            acc.w = fmaf(w, hv.w, acc.w);
        }
        ((float4*)attp)[part * (HH / 4) + dq] = acc;
    }
    __syncthreads();
    if (tid < HH) {
        float s = 0.f;
#pragma unroll
        for (int u = 0; u < 8; ++u) s += attp[u][tid];
        att[tid] = s * inv;
    }
    __syncthreads();

    // ---- Phase D: out[bi,o] = attended @ Wo_w[o,:] + Wo_b[o]
    if (tid < HH) {
        const float4* wrow = (const float4*)(Wo_w + (size_t)tid * HH);
        const float4* av = (const float4*)att;
        float acc2 = Wo_b[tid];
#pragma unroll
        for (int k = 0; k < HH / 4; ++k) {
            float4 w = wrow[k];
            float4 aa = av[k];
            acc2 = fmaf(w.x, aa.x, acc2);
            acc2 = fmaf(w.y, aa.y, acc2);
            acc2 = fmaf(w.z, aa.z, acc2);
            acc2 = fmaf(w.w, aa.w, acc2);
        }
        out[(size_t)bi * HH + tid] = acc2;
    }
}

extern "C" void kernel_launch(void* const* d_in, const int* in_sizes, int n_in,
                              void* d_out, int out_size, void* d_ws, size_t ws_size,
                              hipStream_t stream) {
    const float* x         = (const float*)d_in[0];
    const float* edge_gate = (const float*)d_in[1];
    const float* W_w       = (const float*)d_in[2];
    const float* W_b       = (const float*)d_in[3];
    const float* a         = (const float*)d_in[4];
    const float* Wo_w      = (const float*)d_in[5];
    const float* Wo_b      = (const float*)d_in[6];
    float* out = (float*)d_out;

    float* h_ws  = (float*)d_ws;              // B*V*H floats = 1 MiB
    float* si_ws = h_ws + (size_t)BB * VV * HH;
    float* sj_ws = si_ws + (size_t)BB * VV;

    k_h_scores<<<BB * VV, 128, 0, stream>>>(x, W_w, W_b, a, h_ws, si_ws, sj_ws);
    k_attn<<<BB * VV, 256, 0, stream>>>(edge_gate, h_ws, si_ws, sj_ws, Wo_w, Wo_b, out);
}